// Round 3
// baseline (3829.066 us; speedup 1.0000x reference)
//
#include <hip/hip_runtime.h>
#include <hip/hip_bf16.h>

#define V 10000
#define E 128
#define H1 128
#define H2 64
#define D 64
#define T 512
#define B 256
#define MAXLEN 30
#define SOS 1
#define EOS 2
#define BGS 8          // batch elements per kpred block
#define NVB 40         // v-blocks in kpred ((V+255)/256)

// converted-weight layout offsets (floats) inside ws
#define O_EMB   0
#define O_WIH1  1280000      // + V*E
#define O_WHH1  1378304      // + 512*192
#define O_BIH1  1443840      // + 512*128
#define O_BHH1  1444352      // + 512
#define O_WIH2  1444864      // + 512
#define O_WHH2  1477632      // + 256*128
#define O_BIH2  1494016      // + 256*64
#define O_BHH2  1494272      // + 256
#define O_WQ    1494528      // + 256
#define O_BQ    1498624      // + 64*64
#define O_WP    1498688      // + 64
#define O_BP    2778688      // + 10000*128
#define TOTALW  2788688      // + 10000

typedef unsigned long long u64;

__device__ __forceinline__ float bl(unsigned u){ return __uint_as_float(u << 16); }
__device__ __forceinline__ float bh(unsigned u){ return __uint_as_float(u & 0xFFFF0000u); }
__device__ __forceinline__ float b2f(__hip_bfloat16 x){ return __bfloat162float(x); }
__device__ __forceinline__ float sigf(float x){ return 1.f/(1.f + expf(-x)); }

__device__ __forceinline__ uint4 ldu4(const void* p){
  uint4 r; __builtin_memcpy(&r, p, 16); return r;
}
__device__ __forceinline__ float4 ldf4(const float* p){
  float4 r; __builtin_memcpy(&r, (const void*)p, 16); return r;
}
__device__ __forceinline__ float dot8b(const float* x, uint4 w){
  return x[0]*bl(w.x) + x[1]*bh(w.x) + x[2]*bl(w.y) + x[3]*bh(w.y)
       + x[4]*bl(w.z) + x[5]*bh(w.z) + x[6]*bl(w.w) + x[7]*bh(w.w);
}
__device__ __forceinline__ float dot4f(const float* x, float4 w){
  return x[0]*w.x + x[1]*w.y + x[2]*w.z + x[3]*w.w;
}

// ---------------------------------------------------------------------------
// kdtype: decide whether float tensors are bf16 (flag=1) or fp32 (flag=0).
// For bf16 data, bits[14:7] of each 32-bit word are the low-element's exponent,
// confined to [0x60,0x7E] for ~N(0,0.05^2) values. For fp32 data those bits are
// uniform mantissa bits. 64 words of b_ih1 decide with certainty.
// ---------------------------------------------------------------------------
__global__ void kdtype(const void* __restrict__ probe, int* __restrict__ flagp){
  const int tid = threadIdx.x;                 // 64 threads
  const unsigned w = ((const unsigned*)probe)[tid];
  const unsigned e = (w >> 7) & 0xFFu;
  const bool inband = (e >= 0x60u) && (e <= 0x7Eu);
  const u64 m = __ballot(inband);
  if (tid == 0) flagp[0] = (m == 0xFFFFFFFFFFFFFFFFull) ? 1 : 0;
}

// ---------------------------------------------------------------------------
// kcvt: convert all weight tensors to fp32 into ws (dtype-free hot kernels).
// ---------------------------------------------------------------------------
__global__ __launch_bounds__(256) void kcvt(
    const void* s_emb, const void* s_wih1, const void* s_whh1,
    const void* s_bih1, const void* s_bhh1, const void* s_wih2,
    const void* s_whh2, const void* s_bih2, const void* s_bhh2,
    const void* s_wq, const void* s_bq, const void* s_wp, const void* s_bp,
    float* __restrict__ dst, const int* __restrict__ flagp)
{
  const int idx = blockIdx.x * 256 + threadIdx.x;
  if (idx >= TOTALW) return;
  const int flag = flagp[0];
  const void* src; int off;
  if      (idx < O_WIH1){ src = s_emb;  off = idx - O_EMB;  }
  else if (idx < O_WHH1){ src = s_wih1; off = idx - O_WIH1; }
  else if (idx < O_BIH1){ src = s_whh1; off = idx - O_WHH1; }
  else if (idx < O_BHH1){ src = s_bih1; off = idx - O_BIH1; }
  else if (idx < O_WIH2){ src = s_bhh1; off = idx - O_BHH1; }
  else if (idx < O_WHH2){ src = s_wih2; off = idx - O_WIH2; }
  else if (idx < O_BIH2){ src = s_whh2; off = idx - O_WHH2; }
  else if (idx < O_BHH2){ src = s_bih2; off = idx - O_BIH2; }
  else if (idx < O_WQ)  { src = s_bhh2; off = idx - O_BHH2; }
  else if (idx < O_BQ)  { src = s_wq;   off = idx - O_WQ;   }
  else if (idx < O_WP)  { src = s_bq;   off = idx - O_BQ;   }
  else if (idx < O_BP)  { src = s_wp;   off = idx - O_WP;   }
  else                  { src = s_bp;   off = idx - O_BP;   }
  dst[idx] = flag ? b2f(((const __hip_bfloat16*)src)[off])
                  : ((const float*)src)[off];
}

// ---------------------------------------------------------------------------
// kdec: one block per batch element. argmax-candidate scan -> embedding ->
// LSTM1 -> LSTM2 -> query -> masked softmax attention -> context. fp32 inside.
// ---------------------------------------------------------------------------
__global__ __launch_bounds__(256) void kdec(
    int t,
    const void* __restrict__ enc_key,
    const void* __restrict__ enc_val,
    const int* __restrict__ mask,
    const float* __restrict__ emb_f,
    const float* __restrict__ wih1_f, const float* __restrict__ whh1_f,
    const float* __restrict__ bih1_f, const float* __restrict__ bhh1_f,
    const float* __restrict__ wih2_f, const float* __restrict__ whh2_f,
    const float* __restrict__ bih2_f, const float* __restrict__ bhh2_f,
    const float* __restrict__ wq_f,   const float* __restrict__ bq_f,
    float* __restrict__ h1, float* __restrict__ c1,
    float* __restrict__ h2, float* __restrict__ c2,
    float* __restrict__ ctx, float* __restrict__ xvec,
    const float* __restrict__ candv, const int* __restrict__ candi,
    const int* __restrict__ flagp)
{
  const int b = blockIdx.x;
  const int tid = threadIdx.x;
  const int flagb = flagp[0];

  __shared__ float inp_s[E + D];
  __shared__ float h1_s[H1];
  __shared__ float h2_s[H2];
  __shared__ float g_s[4*H1];
  __shared__ float q_s[D];
  __shared__ float wv_s[T];
  __shared__ float red_s[256];
  __shared__ float cv_s[NVB];
  __shared__ int   ci_s[NVB];
  __shared__ int   tok_s;

  // --- token = argmax over previous step's candidates (first-index tie-break)
  if (t > 0 && tid < NVB){
    cv_s[tid] = candv[b*NVB + tid];
    ci_s[tid] = candi[b*NVB + tid];
  }
  __syncthreads();
  if (tid == 0){
    int tok = SOS;
    if (t > 0){
      float bv = cv_s[0]; int bi = ci_s[0];
      for (int j = 1; j < NVB; ++j)
        if (cv_s[j] > bv){ bv = cv_s[j]; bi = ci_s[j]; }   // strict > keeps earliest
      tok = bi;
    }
    tok_s = tok;
  }
  __syncthreads();
  const int tok = tok_s;

  // --- build inp = [emb_p[tok], context], load recurrent state
  if (tid < E){
    inp_s[tid] = (tok == EOS) ? 0.f : emb_f[(size_t)tok*E + tid];
  } else if (tid < E + D){
    inp_s[tid] = (t == 0) ? 0.f : ctx[b*D + (tid - E)];
  }
  if (tid < H1)                h1_s[tid]       = (t == 0) ? 0.f : h1[b*H1 + tid];
  if (tid >= 128 && tid < 192) h2_s[tid - 128] = (t == 0) ? 0.f : h2[b*H2 + (tid - 128)];
  __syncthreads();

  // --- LSTM1 gates (512 outputs, 2 per thread)
  for (int j = tid; j < 4*H1; j += 256){
    const float* wr = wih1_f + (size_t)j*(E + D);
    float acc = bih1_f[j] + bhh1_f[j];
    #pragma unroll
    for (int kk = 0; kk < (E + D)/4; ++kk) acc += dot4f(inp_s + kk*4, ldf4(wr + kk*4));
    const float* wr2 = whh1_f + (size_t)j*H1;
    #pragma unroll
    for (int kk = 0; kk < H1/4; ++kk) acc += dot4f(h1_s + kk*4, ldf4(wr2 + kk*4));
    g_s[j] = acc;
  }
  __syncthreads();

  // --- LSTM1 update
  if (tid < H1){
    float gi = sigf(g_s[tid]);
    float gf = sigf(g_s[H1 + tid]);
    float gg = tanhf(g_s[2*H1 + tid]);
    float go = sigf(g_s[3*H1 + tid]);
    float cold = (t == 0) ? 0.f : c1[b*H1 + tid];
    float cn = gf*cold + gi*gg;
    float hn = go*tanhf(cn);
    c1[b*H1 + tid] = cn;
    h1[b*H1 + tid] = hn;
    h1_s[tid] = hn;  // h1_new
  }
  __syncthreads();

  // --- LSTM2 gates (256 outputs, 1 per thread)
  {
    const int j = tid;
    const float* wr = wih2_f + (size_t)j*H1;
    float acc = bih2_f[j] + bhh2_f[j];
    #pragma unroll
    for (int kk = 0; kk < H1/4; ++kk) acc += dot4f(h1_s + kk*4, ldf4(wr + kk*4));
    const float* wr2 = whh2_f + (size_t)j*H2;
    #pragma unroll
    for (int kk = 0; kk < H2/4; ++kk) acc += dot4f(h2_s + kk*4, ldf4(wr2 + kk*4));
    g_s[j] = acc;
  }
  __syncthreads();

  // --- LSTM2 update
  if (tid < H2){
    float gi = sigf(g_s[tid]);
    float gf = sigf(g_s[H2 + tid]);
    float gg = tanhf(g_s[2*H2 + tid]);
    float go = sigf(g_s[3*H2 + tid]);
    float cold = (t == 0) ? 0.f : c2[b*H2 + tid];
    float cn = gf*cold + gi*gg;
    float hn = go*tanhf(cn);
    c2[b*H2 + tid] = cn;
    h2[b*H2 + tid] = hn;
    h2_s[tid] = hn;                      // h2_new
    xvec[b*(H2 + D) + tid] = hn;         // first half of pred input
  }
  __syncthreads();

  // --- query = h2_new @ wq.T + bq
  if (tid < D){
    const float* wr = wq_f + (size_t)tid*H2;
    float acc = bq_f[tid];
    #pragma unroll
    for (int kk = 0; kk < H2/4; ++kk) acc += dot4f(h2_s + kk*4, ldf4(wr + kk*4));
    q_s[tid] = acc;
  }
  __syncthreads();

  // --- attention energies for t2 = tid and tid+256
  float e0 = 0.f, e1 = 0.f;
  if (flagb){
    const __hip_bfloat16* base = (const __hip_bfloat16*)enc_key;
    const __hip_bfloat16* kr0 = base + ((size_t)tid*B + b)*D;
    const __hip_bfloat16* kr1 = base + ((size_t)(tid + 256)*B + b)*D;
    #pragma unroll
    for (int kk = 0; kk < D/8; ++kk){
      e0 += dot8b(q_s + kk*8, ldu4(kr0 + kk*8));
      e1 += dot8b(q_s + kk*8, ldu4(kr1 + kk*8));
    }
  } else {
    const float* base = (const float*)enc_key;
    const float* kr0 = base + ((size_t)tid*B + b)*D;
    const float* kr1 = base + ((size_t)(tid + 256)*B + b)*D;
    #pragma unroll
    for (int kk = 0; kk < D/4; ++kk){
      e0 += dot4f(q_s + kk*4, ldf4(kr0 + kk*4));
      e1 += dot4f(q_s + kk*4, ldf4(kr1 + kk*4));
    }
  }
  red_s[tid] = fmaxf(e0, e1);
  __syncthreads();
  for (int s = 128; s > 0; s >>= 1){
    if (tid < s) red_s[tid] = fmaxf(red_s[tid], red_s[tid + s]);
    __syncthreads();
  }
  const float emax = red_s[0];
  __syncthreads();

  // masked softmax weights; mask*exp(e-emax)/sum == reference math (Z cancels)
  const int m0 = mask[b*T + tid], m1 = mask[b*T + tid + 256];
  const float w0 = m0 ? expf(e0 - emax) : 0.f;
  const float w1 = m1 ? expf(e1 - emax) : 0.f;
  wv_s[tid] = w0;
  wv_s[tid + 256] = w1;
  red_s[tid] = w0 + w1;
  __syncthreads();
  for (int s = 128; s > 0; s >>= 1){
    if (tid < s) red_s[tid] += red_s[tid + s];
    __syncthreads();
  }
  const float inv = 1.f / fmaxf(red_s[0], 2e-30f);
  __syncthreads();

  // --- context = (w/sum) . enc_values   (lanes d=0..63 read contiguous)
  {
    const int d = tid & 63, ch = tid >> 6;
    float acc = 0.f;
    if (flagb){
      const __hip_bfloat16* base = (const __hip_bfloat16*)enc_val;
      for (int tt = ch*128; tt < ch*128 + 128; ++tt)
        acc += wv_s[tt] * b2f(base[((size_t)tt*B + b)*D + d]);
    } else {
      const float* base = (const float*)enc_val;
      for (int tt = ch*128; tt < ch*128 + 128; ++tt)
        acc += wv_s[tt] * base[((size_t)tt*B + b)*D + d];
    }
    red_s[tid] = acc;
  }
  __syncthreads();
  if (tid < D){
    float cv = (red_s[tid] + red_s[tid + 64] + red_s[tid + 128] + red_s[tid + 192]) * inv;
    ctx[b*D + tid] = cv;
    xvec[b*(H2 + D) + H2 + tid] = cv;    // second half of pred input
  }
}

// ---------------------------------------------------------------------------
// kpred: pred = xvec @ wp.T + bp, fused store + per-(b, v-block) argmax
// candidate. grid (NVB x B/BGS), 256 threads; thread owns 1 v-row, 8 b's.
// ---------------------------------------------------------------------------
__global__ __launch_bounds__(256) void kpred(
    int t,
    const float* __restrict__ wp_f,
    const float* __restrict__ bp_f,
    const float* __restrict__ xvec,
    void* __restrict__ outv,
    float* __restrict__ candv, int* __restrict__ candi,
    const int* __restrict__ flagp)
{
  const int tid = threadIdx.x;
  const int vb = blockIdx.x;
  const int v = vb * 256 + tid;
  const int bg = blockIdx.y;
  const int flagb = flagp[0];
  const bool valid = v < V;
  const int vc = valid ? v : 0;
  const float* wrow = wp_f + (size_t)vc*(H2 + D);
  const float* xp = xvec + (size_t)bg*BGS*(H2 + D);

  float acc[BGS];
  #pragma unroll
  for (int i = 0; i < BGS; ++i) acc[i] = 0.f;

  #pragma unroll
  for (int kk = 0; kk < (H2 + D)/4; ++kk){
    const float4 w = ldf4(wrow + kk*4);
    #pragma unroll
    for (int i = 0; i < BGS; ++i){
      const float* x = xp + i*(H2 + D) + kk*4;
      acc[i] += x[0]*w.x + x[1]*w.y + x[2]*w.z + x[3]*w.w;
    }
  }

  const float bias = valid ? bp_f[vc] : 0.f;
  #pragma unroll
  for (int i = 0; i < BGS; ++i){
    acc[i] += bias;
    if (valid){
      const size_t oi = ((size_t)(bg*BGS + i)*MAXLEN + t)*V + v;
      if (flagb) ((__hip_bfloat16*)outv)[oi] = __float2bfloat16(acc[i]);
      else       ((float*)outv)[oi] = acc[i];
    }
  }

  // per-b (val, idx) max with first-index tie-break: wave shuffle -> LDS -> ws
  __shared__ float lv[4][BGS];
  __shared__ int   li[4][BGS];
  const int lane = tid & 63, wid = tid >> 6;
  #pragma unroll
  for (int i = 0; i < BGS; ++i){
    float mv = valid ? acc[i] : -__builtin_inff();
    int   mi = valid ? v : 0x7FFFFFFF;
    for (int off = 32; off > 0; off >>= 1){
      float ov = __shfl_down(mv, off);
      int   oi = __shfl_down(mi, off);
      if (ov > mv || (ov == mv && oi < mi)){ mv = ov; mi = oi; }
    }
    if (lane == 0){ lv[wid][i] = mv; li[wid][i] = mi; }
  }
  __syncthreads();
  if (tid < BGS){
    float mv = lv[0][tid]; int mi = li[0][tid];
    #pragma unroll
    for (int w2 = 1; w2 < 4; ++w2){
      float ov = lv[w2][tid]; int oi = li[w2][tid];
      if (ov > mv || (ov == mv && oi < mi)){ mv = ov; mi = oi; }
    }
    const int b = bg*BGS + tid;
    candv[b*NVB + vb] = mv;
    candi[b*NVB + vb] = mi;
  }
}

// ---------------------------------------------------------------------------
extern "C" void kernel_launch(void* const* d_in, const int* in_sizes, int n_in,
                              void* d_out, int out_size, void* d_ws, size_t ws_size,
                              hipStream_t stream)
{
  const void* enc_key = d_in[0];
  const void* enc_val = d_in[1];
  const int*  mask    = (const int*)d_in[2];
  const void* emb     = d_in[3];
  const void* w_ih1   = d_in[4];
  const void* w_hh1   = d_in[5];
  const void* b_ih1   = d_in[6];
  const void* b_hh1   = d_in[7];
  const void* w_ih2   = d_in[8];
  const void* w_hh2   = d_in[9];
  const void* b_ih2   = d_in[10];
  const void* b_hh2   = d_in[11];
  const void* wq      = d_in[12];
  const void* bq      = d_in[13];
  const void* wp      = d_in[14];
  const void* bp      = d_in[15];

  // ws layout: [flag(16f)] [weights fp32 TOTALW] [state]
  float* wsf  = (float*)d_ws;
  int*  flagp = (int*)wsf;
  float* wts  = wsf + 16;
  float* h1    = wts + TOTALW;          // B*H1
  float* c1    = h1   + B*H1;           // B*H1
  float* h2    = c1   + B*H1;           // B*H2
  float* c2    = h2   + B*H2;           // B*H2
  float* ctx   = c2   + B*H2;           // B*D
  float* xvec  = ctx  + B*D;            // B*(H2+D)
  float* candv = xvec + B*(H2 + D);     // B*NVB
  int*   candi = (int*)(candv + B*NVB); // B*NVB

  kdtype<<<dim3(1), dim3(64), 0, stream>>>(b_ih1, flagp);
  kcvt<<<dim3((TOTALW + 255)/256), dim3(256), 0, stream>>>(
      emb, w_ih1, w_hh1, b_ih1, b_hh1, w_ih2, w_hh2, b_ih2, b_hh2,
      wq, bq, wp, bp, wts, flagp);

  for (int t = 0; t < MAXLEN; ++t){
    kdec<<<dim3(B), dim3(256), 0, stream>>>(
        t, enc_key, enc_val, mask,
        wts + O_EMB,
        wts + O_WIH1, wts + O_WHH1, wts + O_BIH1, wts + O_BHH1,
        wts + O_WIH2, wts + O_WHH2, wts + O_BIH2, wts + O_BHH2,
        wts + O_WQ, wts + O_BQ,
        h1, c1, h2, c2, ctx, xvec, candv, candi, flagp);
    kpred<<<dim3(NVB, B/BGS), dim3(256), 0, stream>>>(
        t, wts + O_WP, wts + O_BP, xvec, d_out, candv, candi, flagp);
  }
}